// Round 6
// baseline (412.865 us; speedup 1.0000x reference)
//
#include <hip/hip_runtime.h>
#include <hip/hip_bf16.h>

#define BB   128
#define TT   256
#define CC   384
#define HH   6
#define HSZ  64
#define DFF  1536
#define EPSV 1e-5f
#define RPB  8
#define NTOK (BB * TT)          // 32768
#define NQKV (3 * CC)           // 1152

typedef __attribute__((ext_vector_type(8))) short  short8;
typedef __attribute__((ext_vector_type(4))) float  f32x4;
typedef __hip_bfloat16 bf16;

// async 16B global -> LDS (lane-contiguous at wave-uniform base)
__device__ __forceinline__ void async_copy16(const bf16* g, bf16* l) {
    __builtin_amdgcn_global_load_lds(
        (const __attribute__((address_space(1))) void*)g,
        (__attribute__((address_space(3))) void*)l, 16, 0, 0);
}

// ---------------- block-wide reduction over 384 threads (6 waves) -------------
__device__ __forceinline__ void block_reduce2(float& a, float& b, float* red) {
    #pragma unroll
    for (int off = 32; off > 0; off >>= 1) {
        a += __shfl_down(a, off, 64);
        b += __shfl_down(b, off, 64);
    }
    const int lane = threadIdx.x & 63;
    const int wid  = threadIdx.x >> 6;
    if (lane == 0) { red[wid * 2] = a; red[wid * 2 + 1] = b; }
    __syncthreads();
    if (threadIdx.x == 0) {
        float sa = 0.f, sb = 0.f;
        #pragma unroll
        for (int w = 0; w < 6; ++w) { sa += red[w * 2]; sb += red[w * 2 + 1]; }
        red[12] = sa; red[13] = sb;
    }
    __syncthreads();
    a = red[12]; b = red[13];
}

// ---------------- LN -> bf16 --------------------------------------------------
__global__ __launch_bounds__(CC) void ln_bf16_kernel(
        const float* __restrict__ x, const float* __restrict__ g,
        const float* __restrict__ be, bf16* __restrict__ y) {
    __shared__ float red[16];
    const int tid = threadIdx.x;
    const long row0 = (long)blockIdx.x * RPB;
    const float gg = g[tid], bb = be[tid];
    for (int r = 0; r < RPB; ++r) {
        float v = x[(row0 + r) * CC + tid];
        float s = v, sq = v * v;
        block_reduce2(s, sq, red);
        float mu  = s  * (1.0f / CC);
        float var = sq * (1.0f / CC) - mu * mu;
        float rs  = rsqrtf(var + EPSV);
        y[(row0 + r) * CC + tid] = __float2bfloat16((v - mu) * rs * gg + bb);
        __syncthreads();
    }
}

// ---------------- unified weight packing (all transposes in ONE launch) -------
__global__ __launch_bounds__(256) void pack_weights(
        const float* __restrict__ Wq, const float* __restrict__ Wk,
        const float* __restrict__ Wv, const float* __restrict__ Wo,
        const float* __restrict__ W1, const float* __restrict__ W2,
        bf16* __restrict__ WcatT, bf16* __restrict__ WoT,
        bf16* __restrict__ W1T, bf16* __restrict__ W2T) {
    __shared__ float t[32][33];
    const int id = blockIdx.x;
    const float* in; bf16* out; int R, Cn, c0, r0;
    if (id < 432) {
        const int which = id / 144, rem = id % 144, h = rem / 24, tt = rem % 24;
        const float* W = (which == 0) ? Wq : ((which == 1) ? Wk : Wv);
        in = W + (long)h * CC * HSZ;  R = CC; Cn = HSZ;
        c0 = (tt % 2) * 32; r0 = (tt / 2) * 32;
        out = WcatT + ((long)which * CC + h * HSZ) * CC;
    } else if (id < 576) {
        const int i2 = id - 432;
        in = Wo; out = WoT; R = CC; Cn = CC;
        c0 = (i2 % 12) * 32; r0 = (i2 / 12) * 32;
    } else if (id < 1152) {
        const int i3 = id - 576;
        in = W1; out = W1T; R = CC; Cn = DFF;
        c0 = (i3 % 48) * 32; r0 = (i3 / 48) * 32;
    } else {
        const int i4 = id - 1152;
        in = W2; out = W2T; R = DFF; Cn = CC;
        c0 = (i4 % 12) * 32; r0 = (i4 / 12) * 32;
    }
    const int tid = threadIdx.x, tx = tid & 31, ty = tid >> 5;
    #pragma unroll
    for (int p = 0; p < 4; ++p)
        t[ty + p * 8][tx] = in[(long)(r0 + ty + p * 8) * Cn + c0 + tx];
    __syncthreads();
    #pragma unroll
    for (int p = 0; p < 4; ++p)
        out[(long)(c0 + ty + p * 8) * R + r0 + tx] = __float2bfloat16(t[tx][ty + p * 8]);
}

// ---------------- MFMA GEMM 128x384 full-N panel, 8 waves, counted vmcnt ------
// C[M,N] = A[M,K] * BT[N,K]^T, N-panel = 384 cols per block (nby col-groups).
// Geometry rationale: all our N dims are multiples of 384, so a full 384-wide
// panel stages A ONCE per col-group (vs once per 128-tile) and raises
// FLOP/staged-byte 64 -> 96. Grids become exact: Wo/W2 = 256 blocks = 1/CU.
// Per-CU K-step count drops 3x vs 128x128 tiling -- that's the lever, since
// the 2-phase step overhead (~1.1k cyc) is structural (m233).
// Pipeline (2-deep, counted): tile t in buf t%2.
//   vmcnt(4)  [tile t landed; tile t+1's 4 loads stay in flight]
//   barrier   [per-wave vmcnt -> need all waves' loads landed]
//   ds_read x10 (tile t) ; lgkmcnt(0)
//   barrier   [all waves' reads of buf t%2 retired -> WAR-safe overwrite]
//   stage tile t+2 -> buf t%2 ; 24 MFMA
// vmcnt never drains to 0 mid-loop. LDS = 2*(8KB A + 24KB B) = 64 KB.
// EPI: 1 = bias+relu -> bf16; 2 = bias+residual -> fp32; 3 = bf16 store
template<int K, int EPI>
__global__ __launch_bounds__(512) void gemm_fn(
        const bf16* __restrict__ A, const bf16* __restrict__ BT,
        const float* __restrict__ bias, const float* __restrict__ res,
        float* __restrict__ outF, bf16* __restrict__ outB, int N, int nby) {
    __shared__ bf16 A0[128 * 32];
    __shared__ bf16 A1[128 * 32];
    __shared__ bf16 B0[384 * 32];
    __shared__ bf16 B1[384 * 32];

    const int tid = threadIdx.x;

    // XCD-chunked block swizzle (grid is a multiple of 8)
    const int hwid  = blockIdx.x;
    const int chunk = gridDim.x >> 3;
    const int e     = hwid & 7;
    const int s     = hwid >> 3;
    const int gx    = chunk / nby;
    const int bx    = e * gx + s / nby;
    const int by    = s - (s / nby) * nby;
    const int m0 = bx * 128;
    const int n0 = by * 384;

    const int ln   = tid & 63;
    const int wid  = tid >> 6;          // 0..7
    const int wm   = (wid & 1) * 64;    // M-half
    const int wn   = (wid >> 1) * 96;   // N-quarter (96 = multiple of 32)
    const int fr   = ln & 15;
    const int quad = ln >> 4;
    const int slot = quad ^ ((fr >> 1) & 3);

    // staging coords: A = 512 chunks (1/thread), B = 1536 chunks (3/thread)
    const int rA = tid >> 2, gA = (tid & 3) ^ ((rA >> 1) & 3);
    const long gaA = (long)rA * K + gA * 8;
    const int uB1 = tid + 512, uB2 = tid + 1024;
    const int rB0 = tid >> 2, gB0 = (tid & 3) ^ ((rB0 >> 1) & 3);
    const int rB1 = uB1 >> 2, gB1 = (uB1 & 3) ^ ((rB1 >> 1) & 3);
    const int rB2 = uB2 >> 2, gB2 = (uB2 & 3) ^ ((rB2 >> 1) & 3);
    const long gaB0 = (long)rB0 * K + gB0 * 8;
    const long gaB1 = (long)rB1 * K + gB1 * 8;
    const long gaB2 = (long)rB2 * K + gB2 * 8;
    const bf16* Ap  = A  + (long)m0 * K;
    const bf16* BTp = BT + (long)n0 * K;

    f32x4 acc[4][6];
    #pragma unroll
    for (int i = 0; i < 4; ++i)
        #pragma unroll
        for (int j = 0; j < 6; ++j)
            acc[i][j] = (f32x4){0.f, 0.f, 0.f, 0.f};

    constexpr int NT = K / 32;
    static_assert(NT % 2 == 0, "2-buffer rotation requires even NT");

    auto stage = [&](long k0, bf16* Ad, bf16* Bd) {
        async_copy16(Ap  + gaA  + k0, Ad + tid * 8);
        async_copy16(BTp + gaB0 + k0, Bd + tid * 8);
        async_copy16(BTp + gaB1 + k0, Bd + uB1 * 8);
        async_copy16(BTp + gaB2 + k0, Bd + uB2 * 8);
    };

    auto phase = [&](int t, bf16* Ab, bf16* Bb) {
        if (t + 1 < NT) {
            asm volatile("s_waitcnt vmcnt(4)" ::: "memory");
        } else {
            asm volatile("s_waitcnt vmcnt(0)" ::: "memory");
        }
        __builtin_amdgcn_s_barrier();          // all waves' tile-t loads landed

        short8 af[4], bfr[6];
        #pragma unroll
        for (int i = 0; i < 4; ++i)
            af[i] = *(const short8*)(Ab + (wm + i * 16 + fr) * 32 + slot * 8);
        #pragma unroll
        for (int j = 0; j < 6; ++j)
            bfr[j] = *(const short8*)(Bb + (wn + j * 16 + fr) * 32 + slot * 8);
        asm volatile("s_waitcnt lgkmcnt(0)" ::: "memory");
        __builtin_amdgcn_s_barrier();          // all waves' reads retired
        __builtin_amdgcn_sched_barrier(0);

        if (t + 2 < NT) stage((long)(t + 2) * 32, Ab, Bb);

        #pragma unroll
        for (int i = 0; i < 4; ++i)
            #pragma unroll
            for (int j = 0; j < 6; ++j)
                acc[i][j] = __builtin_amdgcn_mfma_f32_16x16x32_bf16(
                    af[i], bfr[j], acc[i][j], 0, 0, 0);
    };

    // prologue: tiles 0,1 in flight (8 loads/thread)
    stage(0,  A0, B0);
    stage(32, A1, B1);

    for (int t = 0; t < NT; t += 2) {
        phase(t,     A0, B0);
        phase(t + 1, A1, B1);
    }

    #pragma unroll
    for (int i = 0; i < 4; ++i) {
        #pragma unroll
        for (int j = 0; j < 6; ++j) {
            const int col = n0 + wn + j * 16 + fr;
            #pragma unroll
            for (int r = 0; r < 4; ++r) {
                const int row = m0 + wm + i * 16 + quad * 4 + r;
                const long idx = (long)row * N + col;
                float v = acc[i][j][r];
                if (EPI == 1) {
                    v = fmaxf(v + bias[col], 0.f);
                    outB[idx] = __float2bfloat16(v);
                } else if (EPI == 2) {
                    outF[idx] = v + bias[col] + res[idx];
                } else {
                    outB[idx] = __float2bfloat16(v);
                }
            }
        }
    }
}

// ---------------- MFMA causal flash attention ---------------------------------
// Q-tile loop uses CONSTANT bounds + uniform guard so all per-tile state
// (accO/qf/mrow/lrow) is statically indexed -> registers, not scratch.
struct alignas(8) bh4s { bf16 a, b, c, d; };

__global__ __launch_bounds__(256, 2) void attn_mfma_kernel(
        const bf16* __restrict__ qkv, bf16* __restrict__ ab) {
    __shared__ bf16 Kt[64][72];
    __shared__ bf16 Vt[64][72];
    __shared__ bf16 Pb[4][16][72];

    const int tid  = threadIdx.x;
    const int bh   = blockIdx.x;
    const int b    = bh / HH, h = bh % HH;
    const int w    = tid >> 6;
    const int ln   = tid & 63;
    const int ln15 = ln & 15;
    const int quad = ln >> 4;

    short8 qf[4][2];
    #pragma unroll
    for (int i = 0; i < 4; ++i) {
        const long tok = (long)b * TT + w * 16 + i * 64 + ln15;
        const bf16* p = qkv + tok * NQKV + h * HSZ + quad * 8;
        qf[i][0] = *(const short8*)p;
        qf[i][1] = *(const short8*)(p + 32);
    }

    f32x4 accO[4][4];
    float mrow[4][4], lrow[4][4];
    #pragma unroll
    for (int i = 0; i < 4; ++i) {
        #pragma unroll
        for (int j = 0; j < 4; ++j) accO[i][j] = (f32x4){0.f, 0.f, 0.f, 0.f};
        #pragma unroll
        for (int r = 0; r < 4; ++r) { mrow[i][r] = -1e30f; lrow[i][r] = 0.f; }
    }

    for (int sidx = 0; sidx < 4; ++sidx) {
        const int s0 = sidx * 64;
        __syncthreads();
        {
            const bf16* kg = qkv + (long)(b * TT + s0) * NQKV + CC + h * HSZ;
            #pragma unroll
            for (int it = 0; it < 2; ++it) {
                const int u = tid + it * 256;
                const int r = u >> 3, c = (u & 7) * 8;
                *(uint4*)&Kt[r][c] = *(const uint4*)(kg + (long)r * NQKV + c);
            }
            const bf16* vg = qkv + (long)(b * TT + s0) * NQKV + 2 * CC + h * HSZ;
            const int s = tid & 63;
            #pragma unroll
            for (int it = 0; it < 4; ++it) {
                const int dq = (tid >> 6) + it * 4;
                const bh4s vv = *(const bh4s*)(vg + (long)s * NQKV + dq * 4);
                Vt[dq * 4 + 0][s] = vv.a;
                Vt[dq * 4 + 1][s] = vv.b;
                Vt[dq * 4 + 2][s] = vv.c;
                Vt[dq * 4 + 3][s] = vv.d;
            }
        }
        __syncthreads();

        #pragma unroll
        for (int i = 0; i < 4; ++i) {
            if (i < sidx) continue;        // uniform guard; i stays compile-time
            const int rb = w * 16 + i * 64;
            f32x4 S[4];
            #pragma unroll
            for (int jt = 0; jt < 4; ++jt) S[jt] = (f32x4){0.f, 0.f, 0.f, 0.f};
            #pragma unroll
            for (int ks = 0; ks < 2; ++ks) {
                #pragma unroll
                for (int jt = 0; jt < 4; ++jt) {
                    const short8 kf = *(const short8*)&Kt[jt * 16 + ln15][ks * 32 + quad * 8];
                    S[jt] = __builtin_amdgcn_mfma_f32_16x16x32_bf16(qf[i][ks], kf, S[jt], 0, 0, 0);
                }
            }
            float rmax[4];
            #pragma unroll
            for (int r = 0; r < 4; ++r) rmax[r] = -1e30f;
            #pragma unroll
            for (int jt = 0; jt < 4; ++jt) {
                #pragma unroll
                for (int r = 0; r < 4; ++r) {
                    float v = S[jt][r] * 0.125f;
                    if (i == sidx) {
                        const int col = s0 + jt * 16 + ln15;
                        const int row = rb + quad * 4 + r;
                        if (col > row) v = -1e30f;
                    }
                    S[jt][r] = v;
                    rmax[r] = fmaxf(rmax[r], v);
                }
            }
            #pragma unroll
            for (int off = 1; off < 16; off <<= 1)
                #pragma unroll
                for (int r = 0; r < 4; ++r)
                    rmax[r] = fmaxf(rmax[r], __shfl_xor(rmax[r], off, 64));

            float alpha[4], rsum[4];
            #pragma unroll
            for (int r = 0; r < 4; ++r) {
                const float mn = fmaxf(mrow[i][r], rmax[r]);
                alpha[r] = __expf(mrow[i][r] - mn);
                mrow[i][r] = mn;
                rsum[r] = 0.f;
            }
            #pragma unroll
            for (int jt = 0; jt < 4; ++jt)
                #pragma unroll
                for (int r = 0; r < 4; ++r) {
                    const float p = __expf(S[jt][r] - mrow[i][r]);
                    S[jt][r] = p;
                    rsum[r] += p;
                }
            #pragma unroll
            for (int off = 1; off < 16; off <<= 1)
                #pragma unroll
                for (int r = 0; r < 4; ++r)
                    rsum[r] += __shfl_xor(rsum[r], off, 64);
            #pragma unroll
            for (int r = 0; r < 4; ++r)
                lrow[i][r] = lrow[i][r] * alpha[r] + rsum[r];
            #pragma unroll
            for (int jt = 0; jt < 4; ++jt)
                #pragma unroll
                for (int r = 0; r < 4; ++r)
                    accO[i][jt][r] *= alpha[r];

            #pragma unroll
            for (int jt = 0; jt < 4; ++jt)
                #pragma unroll
                for (int r = 0; r < 4; ++r)
                    Pb[w][quad * 4 + r][jt * 16 + ln15] = __float2bfloat16(S[jt][r]);
            const short8 pf0 = *(const short8*)&Pb[w][ln15][quad * 8];
            const short8 pf1 = *(const short8*)&Pb[w][ln15][32 + quad * 8];
            #pragma unroll
            for (int jt = 0; jt < 4; ++jt) {
                const short8 vf0 = *(const short8*)&Vt[jt * 16 + ln15][quad * 8];
                const short8 vf1 = *(const short8*)&Vt[jt * 16 + ln15][32 + quad * 8];
                accO[i][jt] = __builtin_amdgcn_mfma_f32_16x16x32_bf16(pf0, vf0, accO[i][jt], 0, 0, 0);
                accO[i][jt] = __builtin_amdgcn_mfma_f32_16x16x32_bf16(pf1, vf1, accO[i][jt], 0, 0, 0);
            }
        }
    }

    #pragma unroll
    for (int i = 0; i < 4; ++i) {
        const int rb = w * 16 + i * 64;
        float inv[4];
        #pragma unroll
        for (int r = 0; r < 4; ++r) inv[r] = 1.0f / lrow[i][r];
        #pragma unroll
        for (int jt = 0; jt < 4; ++jt)
            #pragma unroll
            for (int r = 0; r < 4; ++r)
                Pb[w][quad * 4 + r][jt * 16 + ln15] = __float2bfloat16(accO[i][jt][r] * inv[r]);
        #pragma unroll
        for (int it = 0; it < 2; ++it) {
            const int u = ln + it * 64;
            const int row = u >> 3, ch = (u & 7) * 8;
            const long tok = (long)b * TT + rb + row;
            *(uint4*)(ab + tok * CC + h * HSZ + ch) = *(const uint4*)&Pb[w][row][ch];
        }
    }
}

// ---------------- launcher ----------------------------------------------------
extern "C" void kernel_launch(void* const* d_in, const int* in_sizes, int n_in,
                              void* d_out, int out_size, void* d_ws, size_t ws_size,
                              hipStream_t stream) {
    const float* x   = (const float*)d_in[0];
    const float* Wq  = (const float*)d_in[1];
    const float* Wk  = (const float*)d_in[2];
    const float* Wv  = (const float*)d_in[3];
    const float* Wo  = (const float*)d_in[4];
    const float* bo  = (const float*)d_in[5];
    const float* W1  = (const float*)d_in[6];
    const float* b1  = (const float*)d_in[7];
    const float* W2  = (const float*)d_in[8];
    const float* b2  = (const float*)d_in[9];
    const float* g1  = (const float*)d_in[10];
    const float* be1 = (const float*)d_in[11];
    const float* g2  = (const float*)d_in[12];
    const float* be2 = (const float*)d_in[13];

    float* out = (float*)d_out;
    char*  ws  = (char*)d_ws;

    const size_t qkvBytes = (size_t)NTOK * NQKV * 4;
    const size_t actOff   = (qkvBytes + 255) & ~(size_t)255;
    const size_t actBytes = (size_t)NTOK * CC * 2;
    size_t wOff = (actOff + actBytes + 255) & ~(size_t)255;

    bf16* qkvb = (bf16*)ws;
    bf16* ff1  = (bf16*)ws;
    bf16* actb = (bf16*)(ws + actOff);

    bf16* WcatT = (bf16*)(ws + wOff); wOff += (size_t)NQKV * CC * 2 + 256;
    bf16* WoT   = (bf16*)(ws + ((wOff + 255) & ~(size_t)255)); wOff = ((wOff + 255) & ~(size_t)255) + (size_t)CC * CC * 2;
    bf16* W1T   = (bf16*)(ws + ((wOff + 255) & ~(size_t)255)); wOff = ((wOff + 255) & ~(size_t)255) + (size_t)DFF * CC * 2;
    bf16* W2T   = (bf16*)(ws + ((wOff + 255) & ~(size_t)255));

    pack_weights<<<1728, 256, 0, stream>>>(Wq, Wk, Wv, Wo, W1, W2,
                                           WcatT, WoT, W1T, W2T);

    ln_bf16_kernel<<<NTOK / RPB, CC, 0, stream>>>(x, g1, be1, actb);
    // QKV: M=32768, 3 col-groups of 384 -> grid 768, 3 blocks/CU
    gemm_fn<CC, 3><<<(NTOK / 128) * 3, 512, 0, stream>>>(
        actb, WcatT, nullptr, nullptr, nullptr, qkvb, NQKV, 3);
    attn_mfma_kernel<<<BB * HH, 256, 0, stream>>>(qkvb, actb);
    // Wo: 1 col-group -> grid 256 = exactly 1 block/CU
    gemm_fn<CC, 2><<<(NTOK / 128), 512, 0, stream>>>(
        actb, WoT, bo, x, out, nullptr, CC, 1);

    ln_bf16_kernel<<<NTOK / RPB, CC, 0, stream>>>(out, g2, be2, actb);
    // W1: 4 col-groups of 384 -> grid 1024
    gemm_fn<CC, 1><<<(NTOK / 128) * 4, 512, 0, stream>>>(
        actb, W1T, b1, nullptr, nullptr, ff1, DFF, 4);
    // W2: K=1536, 1 col-group -> grid 256 = exactly 1 block/CU
    gemm_fn<DFF, 2><<<(NTOK / 128), 512, 0, stream>>>(
        ff1, W2T, b2, out, out, nullptr, CC, 1);
}